// Round 3
// baseline (57.222 us; speedup 1.0000x reference)
//
#include <hip/hip_runtime.h>

// SpikeLoss: loss = 0.5 * sum((outputs - psp(target))^2)
// psp_t = (1/tau) * sum_{s<=t} d^{t-s} x_s, d = 1-1/tau  (T=32, last axis).
// Lane owns 4 consecutive t (one float4); 8 lanes per row. Fully coalesced.
//
// R2: single fused kernel (block partial -> atomicAdd to d_out, memset node zeroes it),
//     U=8 unroll with loads pinned before math via sched_barrier(0)
//     (R1's VGPR=28 proved the compiler sank the loads back into pairs),
//     cndmask-free scan via precomputed per-lane weights.

#define NBLOCKS 2048
#define NTHREADS 256
#define U 8

__global__ __launch_bounds__(NTHREADS) void spike_loss_fused(
    const float* __restrict__ outputs,
    const float* __restrict__ target,
    const int* __restrict__ tau_p,
    float* __restrict__ out,
    int total4)
{
    const float tau = (float)tau_p[0];
    const float d  = 1.0f - 1.0f / tau;   // 0.75 for tau=4 (exact)
    const float inv_tau = 1.0f / tau;
    const float d2 = d * d;
    const float d3 = d2 * d;
    const float d4 = d2 * d2;
    const float d8 = d4 * d4;
    const float d16 = d8 * d8;

    const int lane = threadIdx.x & 63;
    const int j = lane & 7;               // position within 8-lane row segment

    // per-lane scan weights: zero where the shuffle source is outside the segment
    const float w1 = (j >= 1) ? d4  : 0.0f;
    const float w2 = (j >= 2) ? d8  : 0.0f;
    const float w4 = (j >= 4) ? d16 : 0.0f;
    const float c1 = (j >= 1) ? d   : 0.0f;
    const float c2 = (j >= 1) ? d2  : 0.0f;
    const float c3 = (j >= 1) ? d3  : 0.0f;
    const float c4 = (j >= 1) ? d4  : 0.0f;

    const float4* __restrict__ t4 = (const float4*)target;
    const float4* __restrict__ o4 = (const float4*)outputs;

    float acc = 0.0f;
    const int stride = gridDim.x * blockDim.x;
    int g = blockIdx.x * blockDim.x + threadIdx.x;

    for (; g + (U - 1) * stride < total4; g += U * stride) {
        float4 xv[U], ov[U];
        #pragma unroll
        for (int u = 0; u < U; ++u) xv[u] = t4[g + u * stride];
        #pragma unroll
        for (int u = 0; u < U; ++u) ov[u] = o4[g + u * stride];
        // pin all 16 dwordx4 loads before any dependent math
        __builtin_amdgcn_sched_barrier(0);

        #pragma unroll
        for (int u = 0; u < U; ++u) {
            float4 x = xv[u], o = ov[u];
            // local inclusive scan over 4 time steps
            float s0 = x.x;
            float s1 = s0 * d + x.y;
            float s2 = s1 * d + x.z;
            float s3 = s2 * d + x.w;
            // weighted Kogge-Stone across the 8-lane segment (weights, no cndmask)
            float S = s3;
            float u1 = __shfl_up(S, 1, 8); S = fmaf(w1, u1, S);
            float u2 = __shfl_up(S, 2, 8); S = fmaf(w2, u2, S);
            float u4 = __shfl_up(S, 4, 8); S = fmaf(w4, u4, S);
            // carry-in from previous lane's inclusive total
            float cp = __shfl_up(S, 1, 8);  // j==0 gets own S; weights are 0 there
            s0 = fmaf(cp, c1, s0);
            s1 = fmaf(cp, c2, s1);
            s2 = fmaf(cp, c3, s2);
            s3 = fmaf(cp, c4, s3);

            float e0 = fmaf(-inv_tau, s0, o.x);
            float e1 = fmaf(-inv_tau, s1, o.y);
            float e2 = fmaf(-inv_tau, s2, o.z);
            float e3 = fmaf(-inv_tau, s3, o.w);
            acc = fmaf(e0, e0, acc);
            acc = fmaf(e1, e1, acc);
            acc = fmaf(e2, e2, acc);
            acc = fmaf(e3, e3, acc);
        }
    }
    // tail (not taken for the bench shape; segments stay convergent since
    // stride and total4 are multiples of 8)
    for (; g < total4; g += stride) {
        float4 x = t4[g], o = o4[g];
        float s0 = x.x;
        float s1 = s0 * d + x.y;
        float s2 = s1 * d + x.z;
        float s3 = s2 * d + x.w;
        float S = s3;
        float u1 = __shfl_up(S, 1, 8); S = fmaf(w1, u1, S);
        float u2 = __shfl_up(S, 2, 8); S = fmaf(w2, u2, S);
        float u4 = __shfl_up(S, 4, 8); S = fmaf(w4, u4, S);
        float cp = __shfl_up(S, 1, 8);
        s0 = fmaf(cp, c1, s0);
        s1 = fmaf(cp, c2, s1);
        s2 = fmaf(cp, c3, s2);
        s3 = fmaf(cp, c4, s3);
        float e0 = fmaf(-inv_tau, s0, o.x);
        float e1 = fmaf(-inv_tau, s1, o.y);
        float e2 = fmaf(-inv_tau, s2, o.z);
        float e3 = fmaf(-inv_tau, s3, o.w);
        acc = fmaf(e0, e0, acc);
        acc = fmaf(e1, e1, acc);
        acc = fmaf(e2, e2, acc);
        acc = fmaf(e3, e3, acc);
    }

    // wave reduce (64 lanes)
    #pragma unroll
    for (int o = 32; o > 0; o >>= 1) acc += __shfl_down(acc, o, 64);

    __shared__ float wsum[NTHREADS / 64];
    if (lane == 0) wsum[threadIdx.x >> 6] = acc;
    __syncthreads();
    if (threadIdx.x == 0) {
        float s = 0.0f;
        #pragma unroll
        for (int w = 0; w < NTHREADS / 64; ++w) s += wsum[w];
        atomicAdd(out, 0.5f * s);   // 2048 adds spread over the block-drain window
    }
}

extern "C" void kernel_launch(void* const* d_in, const int* in_sizes, int n_in,
                              void* d_out, int out_size, void* d_ws, size_t ws_size,
                              hipStream_t stream) {
    const float* outputs = (const float*)d_in[0];
    const float* target  = (const float*)d_in[1];
    // d_in[2] = n_steps (T=32 baked into the 8-lane-per-row layout)
    const int*   tau_p   = (const int*)d_in[3];

    const int total4 = in_sizes[0] / 4;

    hipMemsetAsync(d_out, 0, sizeof(float), stream);   // graph-capturable memset node
    spike_loss_fused<<<NBLOCKS, NTHREADS, 0, stream>>>(
        outputs, target, tau_p, (float*)d_out, total4);
}